// Round 4
// baseline (541.558 us; speedup 1.0000x reference)
//
#include <hip/hip_runtime.h>
#include <cstdint>
#include <cstddef>

// ---------------------------------------------------------------------------
//   x:    [B=128, T=256, D=1024] fp32
//   Wk:   [1024, 512] per dir    Wr: [128, 512]    bias: [512]
//   xp[dir][t*128+b][512] = x[b,t,:] @ Wk + bias   (bf16, t-major, bias folded)
//   LSTM: 4 seqs/block, 64 blocks of 512 thr (8 waves -> 2 waves/SIMD so
//   LDS/trans latency of one wave hides behind the other's MFMA pipe time).
//   Transposed MFMA (M=gates, N=seqs); z -> LDS -> flat activation
//   (1 cell/thread). Lite barriers (lgkmcnt only, no vmcnt drain).
// ---------------------------------------------------------------------------

typedef __attribute__((ext_vector_type(8))) short short8;
typedef __attribute__((ext_vector_type(4))) float f32x4;
typedef __attribute__((address_space(1))) unsigned int gas_uint;
typedef __attribute__((address_space(3))) unsigned int las_uint;

__device__ __forceinline__ unsigned short f2b(float f) {
    unsigned int u = __float_as_uint(f);
    u += 0x7FFFu + ((u >> 16) & 1u);          // RNE
    return (unsigned short)(u >> 16);
}
__device__ __forceinline__ float b2f(unsigned short u) {
    return __uint_as_float(((unsigned int)u) << 16);
}
__device__ __forceinline__ float sigmoidf_(float z) { return 1.0f / (1.0f + __expf(-z)); }
__device__ __forceinline__ float tanhf_(float z) {
    float e = __expf(2.0f * z);
    return 1.0f - 2.0f / (e + 1.0f);
}

// workgroup barrier WITHOUT the vmcnt(0) drain __syncthreads would emit
#define LITE_BARRIER() asm volatile("s_waitcnt lgkmcnt(0)\n\ts_barrier" ::: "memory")

// async global->LDS 16B
__device__ __forceinline__ void async_ld16(const unsigned short* g, unsigned short* l) {
    __builtin_amdgcn_global_load_lds(
        (gas_uint*)(uintptr_t)g,
        (las_uint*)(uintptr_t)(unsigned int)(uintptr_t)l,
        16, 0, 0);
}

// ---------------------------------------------------------------------------
// Kernel 1: x fp32 -> bf16
// ---------------------------------------------------------------------------
__global__ void conv_x(const float* __restrict__ x, unsigned short* __restrict__ xb, int n8) {
    int idx = blockIdx.x * blockDim.x + threadIdx.x;
    int stride = gridDim.x * blockDim.x;
    for (int i = idx; i < n8; i += stride) {
        const float4* p = ((const float4*)x) + (size_t)i * 2;
        float4 a = p[0], b = p[1];
        short8 r;
        r[0] = (short)f2b(a.x); r[1] = (short)f2b(a.y);
        r[2] = (short)f2b(a.z); r[3] = (short)f2b(a.w);
        r[4] = (short)f2b(b.x); r[5] = (short)f2b(b.y);
        r[6] = (short)f2b(b.z); r[7] = (short)f2b(b.w);
        *(((short8*)xb) + i) = r;
    }
}

// ---------------------------------------------------------------------------
// Kernel 2: transpose + convert Wk [1024][512] -> Wk_t [512][1024] bf16
// ---------------------------------------------------------------------------
__global__ void conv_wk(const float* __restrict__ wf, const float* __restrict__ wb,
                        unsigned short* __restrict__ wt) {
    int dir = blockIdx.y;
    const float* w = dir ? wb : wf;
    int id = blockIdx.x * blockDim.x + threadIdx.x;
    int g = id >> 10, d = id & 1023;
    wt[(size_t)dir * 524288 + id] = f2b(w[d * 512 + g]);
}

// ---------------------------------------------------------------------------
// Kernel 3: GEMM xp = A[32768,1024] @ Wk_t^T + bias -> bf16 t-major [t*128+b][512]
// 128x128 tile, BK=64, global_load_lds w=16, XOR swizzle. min 3 waves/EU.
// ---------------------------------------------------------------------------
__global__ __launch_bounds__(256, 3) void gemm_xp(
    const unsigned short* __restrict__ A,
    const unsigned short* __restrict__ Wt,
    const float* __restrict__ bf_, const float* __restrict__ bb_,
    unsigned short* __restrict__ XP)
{
    __shared__ unsigned short As[128 * 64];
    __shared__ unsigned short Bs[128 * 64];

    const int tid  = threadIdx.x;
    const int dir  = blockIdx.z;
    const int tm   = blockIdx.x;             // 0..255
    const int tn   = blockIdx.y;             // 0..3
    const int w    = tid >> 6;
    const int lane = tid & 63;
    const int lanelo = lane & 15;
    const int quad = lane >> 4;
    const int wm = w & 1, wn = w >> 1;

    const unsigned short* Bmat = Wt + (size_t)dir * 524288;
    const float* bias = dir ? bb_ : bf_;
    unsigned short* out = XP + (size_t)dir * 16777216;

    const unsigned short* ga[4];
    const unsigned short* gb[4];
    unsigned short* la[4];
    unsigned short* lb[4];
#pragma unroll
    for (int c = 0; c < 4; ++c) {
        int p = c * 256 + tid;
        int row = p >> 3;
        int lc = (p & 7) ^ (row & 7);
        ga[c] = A    + (size_t)(tm * 128 + row) * 1024 + lc * 8;
        gb[c] = Bmat + (size_t)(tn * 128 + row) * 1024 + lc * 8;
        int ub = (c * 256 + (tid & ~63)) * 8;
        la[c] = As + ub;
        lb[c] = Bs + ub;
    }

    f32x4 acc[4][4];
#pragma unroll
    for (int i = 0; i < 4; i++)
#pragma unroll
        for (int j = 0; j < 4; j++) acc[i][j] = (f32x4){0.f, 0.f, 0.f, 0.f};

    for (int kt = 0; kt < 16; ++kt) {
        __syncthreads();
#pragma unroll
        for (int c = 0; c < 4; ++c) {
            async_ld16(ga[c] + kt * 64, la[c]);
            async_ld16(gb[c] + kt * 64, lb[c]);
        }
        __syncthreads();
#pragma unroll
        for (int ks = 0; ks < 2; ++ks) {
            short8 af[4], bfr[4];
#pragma unroll
            for (int i = 0; i < 4; ++i) {
                int row = wm * 64 + i * 16 + lanelo;
                af[i] = *(const short8*)(As + row * 64 + (((ks * 4 + quad) ^ (row & 7)) * 8));
            }
#pragma unroll
            for (int j = 0; j < 4; ++j) {
                int row = wn * 64 + j * 16 + lanelo;
                bfr[j] = *(const short8*)(Bs + row * 64 + (((ks * 4 + quad) ^ (row & 7)) * 8));
            }
#pragma unroll
            for (int i = 0; i < 4; ++i)
#pragma unroll
                for (int j = 0; j < 4; ++j)
                    acc[i][j] = __builtin_amdgcn_mfma_f32_16x16x32_bf16(af[i], bfr[j], acc[i][j], 0, 0, 0);
        }
    }

    float biasv[4];
#pragma unroll
    for (int j = 0; j < 4; ++j)
        biasv[j] = bias[tn * 128 + wn * 64 + j * 16 + lanelo];

#pragma unroll
    for (int i = 0; i < 4; ++i) {
#pragma unroll
        for (int r = 0; r < 4; ++r) {
            int gr = tm * 128 + wm * 64 + i * 16 + quad * 4 + r;   // = b*256 + t
            int bb = gr >> 8, tt = gr & 255;
            size_t orow = (size_t)(tt * 128 + bb) * 512;
#pragma unroll
            for (int j = 0; j < 4; ++j) {
                int col = tn * 128 + wn * 64 + j * 16 + lanelo;
                out[orow + col] = f2b(acc[i][j][r] + biasv[j]);
            }
        }
    }
}

// ---------------------------------------------------------------------------
// Kernel 4: LSTM recurrence. 64 blocks x 512 thr (8 waves); block = (dir, 4 seqs).
// Wave w owns gate rows [64w, 64w+64) as Wr^T A-frags (4 M-tiles x 4 K-chains
// = 16 MFMA/wave/step). B = h (cols = seq, 4 valid). 2 waves/SIMD overlap.
// ---------------------------------------------------------------------------
__global__ __launch_bounds__(512, 2) void lstm_rec(
    const unsigned short* __restrict__ XP,    // [2][256*128][512] bf16, bias folded
    const float* __restrict__ Wfr, const float* __restrict__ Wbr,
    float* __restrict__ Hout)                 // [2][128][128]
{
    __shared__ float zbuf[4][520];            // [seq][gate], pad 520 (2-way banks)
    __shared__ unsigned short h_lds[2][4][136]; // [buf][seq][dim], pad 136

    const int tid    = threadIdx.x;
    const int w      = tid >> 6;              // 0..7
    const int lane   = tid & 63;
    const int lanelo = lane & 15;
    const int quad   = lane >> 4;
    const int dir    = blockIdx.x >> 5;
    const int b0     = (blockIdx.x & 31) * 4;

    const float* Wr = dir ? Wbr : Wfr;
    const unsigned short* xp = XP + (size_t)dir * 16777216;

    // --- one-time: Wr^T A-fragments; wave w owns gate rows [64w, 64w+64) ---
    short8 wrf[4][4];
#pragma unroll
    for (int kt = 0; kt < 4; ++kt) {
        int g = 64 * w + 16 * kt + lanelo;
#pragma unroll
        for (int ks = 0; ks < 4; ++ks) {
            short8 f;
#pragma unroll
            for (int j = 0; j < 8; ++j)
                f[j] = (short)f2b(Wr[(ks * 32 + quad * 8 + j) * 512 + g]);
            wrf[kt][ks] = f;
        }
    }

    // activation cell owned by this thread
    const int aseq = tid >> 7;               // 0..3
    const int adim = tid & 127;              // 0..127
    const int arow = b0 + aseq;              // batch index

    if (tid < 4 * 136) ((unsigned short*)h_lds[0])[tid] = 0;

    float c_val = 0.0f;
    float h_val = 0.0f;

    auto xaddr = [&](int t, int g) {
        int rt = dir ? (255 - t) : t;
        return xp + (size_t)rt * 65536 + (size_t)arow * 512 + g * 128 + adim;
    };

    unsigned int xA[4], xB[4];
#pragma unroll
    for (int g = 0; g < 4; ++g) xA[g] = *xaddr(0, g);
#pragma unroll
    for (int g = 0; g < 4; ++g) xB[g] = *xaddr(1, g);

    LITE_BARRIER();                           // h_lds[0] zeros visible

    for (int t = 0; t < 256; ++t) {
        const int cur = t & 1, nxt = cur ^ 1;

        // prefetch xp for t+2 (stays in flight across lite barriers)
        unsigned int xN[4];
        if (t + 2 < 256) {
#pragma unroll
            for (int g = 0; g < 4; ++g) xN[g] = *xaddr(t + 2, g);
        }

        // B-fragments of h (n = seq; lanes with lanelo>=4 replicate seq lanelo&3)
        short8 hb[4];
#pragma unroll
        for (int ks = 0; ks < 4; ++ks)
            hb[ks] = *(const short8*)(&h_lds[cur][lanelo & 3][ks * 32 + quad * 8]);

        // z = Wr^T tiles @ h : D[m=gate][n=seq], 16 MFMA (4 indep chains of 4)
        f32x4 z[4];
#pragma unroll
        for (int kt = 0; kt < 4; ++kt) {
            f32x4 a = (f32x4){0.f, 0.f, 0.f, 0.f};
#pragma unroll
            for (int ks = 0; ks < 4; ++ks)
                a = __builtin_amdgcn_mfma_f32_16x16x32_bf16(wrf[kt][ks], hb[ks], a, 0, 0, 0);
            z[kt] = a;
        }

        // scatter z: C/D row = quad*4+r (gate sub-row), col = lanelo (seq<4)
        if (lanelo < 4) {
#pragma unroll
            for (int kt = 0; kt < 4; ++kt)
                *(f32x4*)(&zbuf[lanelo][64 * w + 16 * kt + quad * 4]) = z[kt];
        }

        LITE_BARRIER();                       // z visible

        float zi = zbuf[aseq][adim]       + b2f((unsigned short)xA[0]);
        float zf = zbuf[aseq][128 + adim] + b2f((unsigned short)xA[1]);
        float zg = zbuf[aseq][256 + adim] + b2f((unsigned short)xA[2]);
        float zo = zbuf[aseq][384 + adim] + b2f((unsigned short)xA[3]);

        float iv = sigmoidf_(zi);
        float fv = sigmoidf_(zf);
        float gv = tanhf_(zg);
        float ov = sigmoidf_(zo);
        c_val = fv * c_val + iv * gv;
        h_val = ov * tanhf_(c_val);

        h_lds[nxt][aseq][adim] = f2b(h_val);

#pragma unroll
        for (int g = 0; g < 4; ++g) { xA[g] = xB[g]; xB[g] = xN[g]; }

        LITE_BARRIER();                       // h(t) visible, zbuf reads done
    }

    Hout[(size_t)(dir * 128 + arow) * 128 + adim] = h_val;
}

// ---------------------------------------------------------------------------
// Kernel 5: MLP head
// ---------------------------------------------------------------------------
__global__ void mlp_head(const float* __restrict__ Hout,
                         const float* __restrict__ W1, const float* __restrict__ b1,
                         const float* __restrict__ W2, const float* __restrict__ b2,
                         float* __restrict__ out)
{
    __shared__ float y1[32];
    int b = blockIdx.x;
    int j = threadIdx.x;
    const float* hf = Hout + (size_t)b * 128;
    const float* hb = Hout + (size_t)(128 + b) * 128;
    if (j < 32) {
        float acc = b1[j];
        for (int k = 0; k < 128; ++k) acc += hf[k] * W1[k * 32 + j];
        for (int k = 0; k < 128; ++k) acc += hb[k] * W1[(128 + k) * 32 + j];
        y1[j] = fmaxf(acc, 0.0f);
    }
    __syncthreads();
    if (j < 2) {
        float z = b2[j];
        for (int k = 0; k < 32; ++k) z += y1[k] * W2[k * 2 + j];
        out[b * 2 + j] = 1.0f / (1.0f + __expf(-z));
    }
}

// ---------------------------------------------------------------------------
extern "C" void kernel_launch(void* const* d_in, const int* in_sizes, int n_in,
                              void* d_out, int out_size, void* d_ws, size_t ws_size,
                              hipStream_t stream) {
    const float* x    = (const float*)d_in[0];
    const float* Wf_k = (const float*)d_in[1];
    const float* Wf_r = (const float*)d_in[2];
    const float* bf   = (const float*)d_in[3];
    const float* Wb_k = (const float*)d_in[4];
    const float* Wb_r = (const float*)d_in[5];
    const float* bb   = (const float*)d_in[6];
    const float* W1   = (const float*)d_in[7];
    const float* b1   = (const float*)d_in[8];
    const float* W2   = (const float*)d_in[9];
    const float* b2   = (const float*)d_in[10];
    float* out = (float*)d_out;

    char* ws = (char*)d_ws;
    const size_t OFF_XB   = 0;                        // 67,108,864 B
    const size_t OFF_WT   = 67108864;                 //  2,097,152 B
    const size_t OFF_HOUT = OFF_WT + 2097152;         //    131,072 B
    const size_t OFF_XP   = OFF_HOUT + 131072;        // 67,108,864 B (bf16)

    unsigned short* xb = (unsigned short*)(ws + OFF_XB);
    unsigned short* wt = (unsigned short*)(ws + OFF_WT);
    float*          ho = (float*)(ws + OFF_HOUT);
    unsigned short* xp = (unsigned short*)(ws + OFF_XP);

    conv_x<<<dim3(2048), dim3(256), 0, stream>>>(x, xb, 33554432 / 8);
    conv_wk<<<dim3(2048, 2), dim3(256), 0, stream>>>(Wf_k, Wb_k, wt);
    gemm_xp<<<dim3(256, 4, 2), dim3(256), 0, stream>>>(xb, wt, bf, bb, xp);
    lstm_rec<<<dim3(64), dim3(512), 0, stream>>>(xp, Wf_r, Wb_r, ho);
    mlp_head<<<dim3(128), dim3(64), 0, stream>>>(ho, W1, b1, W2, b2, out);
}

// Round 5
// 529.339 us; speedup vs baseline: 1.0231x; 1.0231x over previous
//
#include <hip/hip_runtime.h>
#include <cstdint>
#include <cstddef>

// ---------------------------------------------------------------------------
//   x:    [B=128, T=256, D=1024] fp32
//   Wk:   [1024, 512] per dir    Wr: [128, 512]    bias: [512]
//   xp[dir][t*128+b][512] = x[b,t,:] @ Wk + bias   (bf16, t-major, bias folded)
//   LSTM: 4 seqs/block, 64 blocks of 512 thr. Transposed MFMA (M=gates,
//   N=seqs); z -> LDS -> flat activation (1 cell/thread). Unrolled x2,
//   scalar row addressing, lite barriers (no vmcnt drain).
// ---------------------------------------------------------------------------

typedef __attribute__((ext_vector_type(8))) short short8;
typedef __attribute__((ext_vector_type(4))) float f32x4;
typedef __attribute__((address_space(1))) unsigned int gas_uint;
typedef __attribute__((address_space(3))) unsigned int las_uint;

__device__ __forceinline__ unsigned short f2b(float f) {
    unsigned int u = __float_as_uint(f);
    u += 0x7FFFu + ((u >> 16) & 1u);          // RNE
    return (unsigned short)(u >> 16);
}
__device__ __forceinline__ float b2f(unsigned short u) {
    return __uint_as_float(((unsigned int)u) << 16);
}
__device__ __forceinline__ float sigmoidf_(float z) { return 1.0f / (1.0f + __expf(-z)); }
__device__ __forceinline__ float tanhf_(float z) {
    float e = __expf(2.0f * z);
    return 1.0f - 2.0f / (e + 1.0f);
}

// workgroup barrier WITHOUT the vmcnt(0) drain __syncthreads would emit
#define LITE_BARRIER() asm volatile("s_waitcnt lgkmcnt(0)\n\ts_barrier" ::: "memory")

// async global->LDS 16B
__device__ __forceinline__ void async_ld16(const unsigned short* g, unsigned short* l) {
    __builtin_amdgcn_global_load_lds(
        (gas_uint*)(uintptr_t)g,
        (las_uint*)(uintptr_t)(unsigned int)(uintptr_t)l,
        16, 0, 0);
}

// ---------------------------------------------------------------------------
// Kernel 1: x fp32 -> bf16
// ---------------------------------------------------------------------------
__global__ void conv_x(const float* __restrict__ x, unsigned short* __restrict__ xb, int n8) {
    int idx = blockIdx.x * blockDim.x + threadIdx.x;
    int stride = gridDim.x * blockDim.x;
    for (int i = idx; i < n8; i += stride) {
        const float4* p = ((const float4*)x) + (size_t)i * 2;
        float4 a = p[0], b = p[1];
        short8 r;
        r[0] = (short)f2b(a.x); r[1] = (short)f2b(a.y);
        r[2] = (short)f2b(a.z); r[3] = (short)f2b(a.w);
        r[4] = (short)f2b(b.x); r[5] = (short)f2b(b.y);
        r[6] = (short)f2b(b.z); r[7] = (short)f2b(b.w);
        *(((short8*)xb) + i) = r;
    }
}

// ---------------------------------------------------------------------------
// Kernel 2: transpose + convert Wk [1024][512] -> Wk_t [512][1024] bf16
// ---------------------------------------------------------------------------
__global__ void conv_wk(const float* __restrict__ wf, const float* __restrict__ wb,
                        unsigned short* __restrict__ wt) {
    int dir = blockIdx.y;
    const float* w = dir ? wb : wf;
    int id = blockIdx.x * blockDim.x + threadIdx.x;
    int g = id >> 10, d = id & 1023;
    wt[(size_t)dir * 524288 + id] = f2b(w[d * 512 + g]);
}

// ---------------------------------------------------------------------------
// Kernel 3: GEMM xp = A[32768,1024] @ Wk_t^T + bias -> bf16 t-major [t*128+b][512]
// 128x128 tile, BK=64, global_load_lds w=16, XOR swizzle.
// Grid (8, 256): the 8 (tn,dir) blocks sharing A-rows dispatch adjacently.
// ---------------------------------------------------------------------------
__global__ __launch_bounds__(256, 2) void gemm_xp(
    const unsigned short* __restrict__ A,
    const unsigned short* __restrict__ Wt,
    const float* __restrict__ bf_, const float* __restrict__ bb_,
    unsigned short* __restrict__ XP)
{
    __shared__ unsigned short As[128 * 64];
    __shared__ unsigned short Bs[128 * 64];

    const int tid  = threadIdx.x;
    const int tn   = blockIdx.x & 3;         // 0..3
    const int dir  = blockIdx.x >> 2;        // 0..1
    const int tm   = blockIdx.y;             // 0..255
    const int w    = tid >> 6;
    const int lane = tid & 63;
    const int lanelo = lane & 15;
    const int quad = lane >> 4;
    const int wm = w & 1, wn = w >> 1;

    const unsigned short* Bmat = Wt + (size_t)dir * 524288;
    const float* bias = dir ? bb_ : bf_;
    unsigned short* out = XP + (size_t)dir * 16777216;

    const unsigned short* ga[4];
    const unsigned short* gb[4];
    unsigned short* la[4];
    unsigned short* lb[4];
#pragma unroll
    for (int c = 0; c < 4; ++c) {
        int p = c * 256 + tid;
        int row = p >> 3;
        int lc = (p & 7) ^ (row & 7);
        ga[c] = A    + (size_t)(tm * 128 + row) * 1024 + lc * 8;
        gb[c] = Bmat + (size_t)(tn * 128 + row) * 1024 + lc * 8;
        int ub = (c * 256 + (tid & ~63)) * 8;
        la[c] = As + ub;
        lb[c] = Bs + ub;
    }

    f32x4 acc[4][4];
#pragma unroll
    for (int i = 0; i < 4; i++)
#pragma unroll
        for (int j = 0; j < 4; j++) acc[i][j] = (f32x4){0.f, 0.f, 0.f, 0.f};

    for (int kt = 0; kt < 16; ++kt) {
        __syncthreads();
#pragma unroll
        for (int c = 0; c < 4; ++c) {
            async_ld16(ga[c] + kt * 64, la[c]);
            async_ld16(gb[c] + kt * 64, lb[c]);
        }
        __syncthreads();
#pragma unroll
        for (int ks = 0; ks < 2; ++ks) {
            short8 af[4], bfr[4];
#pragma unroll
            for (int i = 0; i < 4; ++i) {
                int row = wm * 64 + i * 16 + lanelo;
                af[i] = *(const short8*)(As + row * 64 + (((ks * 4 + quad) ^ (row & 7)) * 8));
            }
#pragma unroll
            for (int j = 0; j < 4; ++j) {
                int row = wn * 64 + j * 16 + lanelo;
                bfr[j] = *(const short8*)(Bs + row * 64 + (((ks * 4 + quad) ^ (row & 7)) * 8));
            }
#pragma unroll
            for (int i = 0; i < 4; ++i)
#pragma unroll
                for (int j = 0; j < 4; ++j)
                    acc[i][j] = __builtin_amdgcn_mfma_f32_16x16x32_bf16(af[i], bfr[j], acc[i][j], 0, 0, 0);
        }
    }

    float biasv[4];
#pragma unroll
    for (int j = 0; j < 4; ++j)
        biasv[j] = bias[tn * 128 + wn * 64 + j * 16 + lanelo];

#pragma unroll
    for (int i = 0; i < 4; ++i) {
#pragma unroll
        for (int r = 0; r < 4; ++r) {
            int gr = tm * 128 + wm * 64 + i * 16 + quad * 4 + r;   // = b*256 + t
            int bb = gr >> 8, tt = gr & 255;
            size_t orow = (size_t)(tt * 128 + bb) * 512;
#pragma unroll
            for (int j = 0; j < 4; ++j) {
                int col = tn * 128 + wn * 64 + j * 16 + lanelo;
                out[orow + col] = f2b(acc[i][j][r] + biasv[j]);
            }
        }
    }
}

// ---------------------------------------------------------------------------
// Kernel 4: LSTM recurrence. 64 blocks x 512 thr (8 waves); block = (dir, 4 seqs).
// Wave w owns gate rows [64w,64w+64) as Wr^T A-frags. B = h (4 valid cols).
// Unrolled x2; scalar xp row base; 2 lite barriers/step.
// ---------------------------------------------------------------------------
__global__ __launch_bounds__(512, 2) void lstm_rec(
    const unsigned short* __restrict__ XP,    // [2][256*128][512] bf16, bias folded
    const float* __restrict__ Wfr, const float* __restrict__ Wbr,
    float* __restrict__ Hout)                 // [2][128][128]
{
    __shared__ float zbuf[2][4][520];         // [buf][seq][gate]
    __shared__ unsigned short h_lds[2][4][136]; // [buf][seq][dim]

    const int tid    = threadIdx.x;
    const int w      = tid >> 6;              // 0..7
    const int lane   = tid & 63;
    const int lanelo = lane & 15;
    const int quad   = lane >> 4;
    const int dir    = blockIdx.x >> 5;
    const int b0     = (blockIdx.x & 31) * 4;

    const float* Wr = dir ? Wbr : Wfr;
    const unsigned short* xp = XP + (size_t)dir * 16777216;

    // --- one-time: Wr^T A-fragments; wave w owns gate rows [64w, 64w+64) ---
    short8 wrf[4][4];
#pragma unroll
    for (int kt = 0; kt < 4; ++kt) {
        int g = 64 * w + 16 * kt + lanelo;
#pragma unroll
        for (int ks = 0; ks < 4; ++ks) {
            short8 f;
#pragma unroll
            for (int j = 0; j < 8; ++j)
                f[j] = (short)f2b(Wr[(ks * 32 + quad * 8 + j) * 512 + g]);
            wrf[kt][ks] = f;
        }
    }

    // activation cell owned by this thread
    const int aseq = tid >> 7;               // 0..3
    const int adim = tid & 127;              // 0..127
    const int arow = b0 + aseq;              // batch index
    const int voff = arow * 512 + adim;      // lane offset into an xp row (elems)

    if (tid < 4 * 136) ((unsigned short*)h_lds[0])[tid] = 0;

    float c_val = 0.0f;
    float h_val = 0.0f;

    // scalar (wave-uniform) xp row pointer for step t
    auto rowp = [&](int t) {
        int tc = t > 255 ? 255 : t;               // clamp (prefetch overrun)
        int rt = dir ? (255 - tc) : tc;
        return xp + (size_t)rt * 65536;
    };

    unsigned short xA[4], xB[4];
    {
        const unsigned short* r0 = rowp(0);
        const unsigned short* r1 = rowp(1);
#pragma unroll
        for (int g = 0; g < 4; ++g) xA[g] = r0[voff + g * 128];
#pragma unroll
        for (int g = 0; g < 4; ++g) xB[g] = r1[voff + g * 128];
    }

    LITE_BARRIER();                           // h_lds[0] zeros visible

#pragma unroll 1
    for (int tt = 0; tt < 256; tt += 2) {
#pragma unroll
        for (int half = 0; half < 2; ++half) {
            const int cur = half, nxt = half ^ 1;
            const int t = tt + half;
            unsigned short* xcur = half ? xB : xA;

            // B-fragments of h
            short8 hb[4];
#pragma unroll
            for (int ks = 0; ks < 4; ++ks)
                hb[ks] = *(const short8*)(&h_lds[cur][lanelo & 3][ks * 32 + quad * 8]);

            // z = Wr^T tiles @ h : 16 MFMA (4 indep chains of 4)
            f32x4 z[4];
#pragma unroll
            for (int kt = 0; kt < 4; ++kt) {
                f32x4 a = (f32x4){0.f, 0.f, 0.f, 0.f};
#pragma unroll
                for (int ks = 0; ks < 4; ++ks)
                    a = __builtin_amdgcn_mfma_f32_16x16x32_bf16(wrf[kt][ks], hb[ks], a, 0, 0, 0);
                z[kt] = a;
            }

            // scatter z: row = quad*4+r (gate sub-row), col = lanelo (seq<4)
            if (lanelo < 4) {
#pragma unroll
                for (int kt = 0; kt < 4; ++kt)
                    *(f32x4*)(&zbuf[cur][lanelo][64 * w + 16 * kt + quad * 4]) = z[kt];
            }

            LITE_BARRIER();                   // z visible

            const float* zrow = zbuf[cur][aseq];
            float zi = zrow[adim]       + b2f(xcur[0]);
            float zf = zrow[128 + adim] + b2f(xcur[1]);
            float zg = zrow[256 + adim] + b2f(xcur[2]);
            float zo = zrow[384 + adim] + b2f(xcur[3]);

            float iv = sigmoidf_(zi);
            float fv = sigmoidf_(zf);
            float gv = tanhf_(zg);
            float ov = sigmoidf_(zo);
            c_val = fv * c_val + iv * gv;
            h_val = ov * tanhf_(c_val);

            h_lds[nxt][aseq][adim] = f2b(h_val);

            // refill this half's prefetch regs for t+2 (scalar base, fixed voff)
            {
                const unsigned short* rn = rowp(t + 2);
#pragma unroll
                for (int g = 0; g < 4; ++g) xcur[g] = rn[voff + g * 128];
            }

            LITE_BARRIER();                   // h(t) visible, zbuf reads done
        }
    }

    Hout[(size_t)(dir * 128 + arow) * 128 + adim] = h_val;
}

// ---------------------------------------------------------------------------
// Kernel 5: MLP head
// ---------------------------------------------------------------------------
__global__ void mlp_head(const float* __restrict__ Hout,
                         const float* __restrict__ W1, const float* __restrict__ b1,
                         const float* __restrict__ W2, const float* __restrict__ b2,
                         float* __restrict__ out)
{
    __shared__ float y1[32];
    int b = blockIdx.x;
    int j = threadIdx.x;
    const float* hf = Hout + (size_t)b * 128;
    const float* hb = Hout + (size_t)(128 + b) * 128;
    if (j < 32) {
        float acc = b1[j];
        for (int k = 0; k < 128; ++k) acc += hf[k] * W1[k * 32 + j];
        for (int k = 0; k < 128; ++k) acc += hb[k] * W1[(128 + k) * 32 + j];
        y1[j] = fmaxf(acc, 0.0f);
    }
    __syncthreads();
    if (j < 2) {
        float z = b2[j];
        for (int k = 0; k < 32; ++k) z += y1[k] * W2[k * 2 + j];
        out[b * 2 + j] = 1.0f / (1.0f + __expf(-z));
    }
}

// ---------------------------------------------------------------------------
extern "C" void kernel_launch(void* const* d_in, const int* in_sizes, int n_in,
                              void* d_out, int out_size, void* d_ws, size_t ws_size,
                              hipStream_t stream) {
    const float* x    = (const float*)d_in[0];
    const float* Wf_k = (const float*)d_in[1];
    const float* Wf_r = (const float*)d_in[2];
    const float* bf   = (const float*)d_in[3];
    const float* Wb_k = (const float*)d_in[4];
    const float* Wb_r = (const float*)d_in[5];
    const float* bb   = (const float*)d_in[6];
    const float* W1   = (const float*)d_in[7];
    const float* b1   = (const float*)d_in[8];
    const float* W2   = (const float*)d_in[9];
    const float* b2   = (const float*)d_in[10];
    float* out = (float*)d_out;

    char* ws = (char*)d_ws;
    const size_t OFF_XB   = 0;                        // 67,108,864 B
    const size_t OFF_WT   = 67108864;                 //  2,097,152 B
    const size_t OFF_HOUT = OFF_WT + 2097152;         //    131,072 B
    const size_t OFF_XP   = OFF_HOUT + 131072;        // 67,108,864 B (bf16)

    unsigned short* xb = (unsigned short*)(ws + OFF_XB);
    unsigned short* wt = (unsigned short*)(ws + OFF_WT);
    float*          ho = (float*)(ws + OFF_HOUT);
    unsigned short* xp = (unsigned short*)(ws + OFF_XP);

    conv_x<<<dim3(2048), dim3(256), 0, stream>>>(x, xb, 33554432 / 8);
    conv_wk<<<dim3(2048, 2), dim3(256), 0, stream>>>(Wf_k, Wb_k, wt);
    gemm_xp<<<dim3(8, 256), dim3(256), 0, stream>>>(xb, wt, bf, bb, xp);
    lstm_rec<<<dim3(64), dim3(512), 0, stream>>>(xp, Wf_r, Wb_r, ho);
    mlp_head<<<dim3(128), dim3(64), 0, stream>>>(ho, W1, b1, W2, b2, out);
}